// Round 5
// baseline (59.132 us; speedup 1.0000x reference)
//
#include <hip/hip_runtime.h>

// ParabolicPool2D: out[b,c,i,j] = max_{p,q} f[b,c,2i+p,2j+q] - z[p,q]*t[c]
// z = [[1,.5,1],[.5,0,.5],[1,.5,1]]  -> corners: -t, edges: -0.5t, center: 0
// B=16, C=256, H=W=128, ks=3, stride=2 -> oH=oW=63
//
// v5: v4's structure (2 vertically-adjacent outputs/thread, 5 input rows,
// shared middle row), but each row read as float2([2j,2j+1]) + scalar(2j+2).
// The float2 is perfectly coalesced: 64 lanes x 8B = contiguous 512B/instr.
// 10 load instrs/thread vs v4's 15.

#define C_DIM 256
#define H_DIM 128
#define W_DIM 128
#define OH 63
#define OW 63
#define PAIRS 32   // pair ip covers output rows 2ip, 2ip+1

__global__ __launch_bounds__(256) void parab_pool_v5(
    const float* __restrict__ f,
    const float* __restrict__ t,
    float* __restrict__ out)
{
    int idx = blockIdx.x * blockDim.x + threadIdx.x;

    int j   = idx % OW;
    int tmp = idx / OW;
    int ip  = tmp % PAIRS;
    int bc  = tmp / PAIRS;
    int c   = bc & (C_DIM - 1);

    const float a  = -t[c];       // corner offset
    const float ha = 0.5f * a;    // edge offset

    const int i0 = 2 * ip;
    const bool has2 = (i0 + 1 < OH);       // ip==31 -> only one output row

    const int r0 = 4 * ip;                  // input rows r0..r0+4
    const int r3 = has2 ? r0 + 3 : r0 + 1;  // clamped in-bounds duplicates
    const int r4 = has2 ? r0 + 4 : r0 + 2;

    const float* img = f + (size_t)bc * (H_DIM * W_DIM) + 2 * j;

    const float* p0 = img + (size_t)r0 * W_DIM;
    const float* p1 = img + (size_t)(r0 + 1) * W_DIM;
    const float* p2 = img + (size_t)(r0 + 2) * W_DIM;
    const float* p3 = img + (size_t)r3 * W_DIM;
    const float* p4 = img + (size_t)r4 * W_DIM;

    // perfectly-coalesced pair loads + L1-hit tail loads
    float2 A = *(const float2*)p0;  float a2 = p0[2];
    float2 B = *(const float2*)p1;  float b2 = p1[2];
    float2 Cc = *(const float2*)p2; float c2 = p2[2];
    float2 D = *(const float2*)p3;  float d2 = p3[2];
    float2 E = *(const float2*)p4;  float e2 = p4[2];

    // output row i0: rows A,B,C
    float cor0 = fmaxf(fmaxf(A.x, a2), fmaxf(Cc.x, c2));
    float edg0 = fmaxf(fmaxf(A.y, Cc.y), fmaxf(B.x, b2));
    float v0   = fmaxf(B.y, fmaxf(cor0 + a, edg0 + ha));

    // output row i0+1: rows C,D,E
    float cor1 = fmaxf(fmaxf(Cc.x, c2), fmaxf(E.x, e2));
    float edg1 = fmaxf(fmaxf(Cc.y, E.y), fmaxf(D.x, d2));
    float v1   = fmaxf(D.y, fmaxf(cor1 + a, edg1 + ha));

    float* o = out + ((size_t)bc * OH + i0) * OW + j;
    o[0] = v0;
    if (has2) o[OW] = v1;
}

extern "C" void kernel_launch(void* const* d_in, const int* in_sizes, int n_in,
                              void* d_out, int out_size, void* d_ws, size_t ws_size,
                              hipStream_t stream)
{
    const float* f = (const float*)d_in[0];
    const float* t = (const float*)d_in[1];
    float* out = (float*)d_out;

    int total = 16 * C_DIM * PAIRS * OW;   // 8,257,536
    int block = 256;
    int grid = total / block;              // 32256, exact

    parab_pool_v5<<<grid, block, 0, stream>>>(f, t, out);
}